// Round 1
// baseline (428.107 us; speedup 1.0000x reference)
//
#include <hip/hip_runtime.h>

#define BATCH   8
#define LENGTH  4096
#define IN_DIM  512
#define STATE   256
#define OUT_DIM 512
#define NC      64          // chunks along L
#define LC      64          // LENGTH / NC

// ---------------------------------------------------------------------------
// Generic fp32 tiled GEMM: C[M,N] = A[M,K] * B[K,N], all row-major.
// 64x64 tile, BK=16, 256 threads, each thread computes 4x4 outputs.
// M,N multiples of 64; K multiple of 16 (true for both our GEMMs).
// ---------------------------------------------------------------------------
#define TILE 64
#define BK   16

__global__ __launch_bounds__(256) void gemm_f32_tile64(
    const float* __restrict__ A, const float* __restrict__ B,
    float* __restrict__ C, int M, int N, int K)
{
    __shared__ float As[BK][TILE + 1];   // As[k][m], padded vs 16-way store conflict
    __shared__ float Bs[BK][TILE + 1];   // Bs[k][n]

    const int tid = threadIdx.x;
    const int tx = tid & 15;     // 0..15 col group
    const int ty = tid >> 4;     // 0..15 row group
    const int rowBase = blockIdx.y * TILE;
    const int colBase = blockIdx.x * TILE;

    float acc[4][4] = {};

    for (int k0 = 0; k0 < K; k0 += BK) {
        // Load A tile: 64 rows x 16 k (k fastest across lanes -> 64B segments)
        #pragma unroll
        for (int i = 0; i < 4; ++i) {
            int idx = tid + i * 256;
            int m = idx >> 4;
            int k = idx & 15;
            As[k][m] = A[(size_t)(rowBase + m) * K + k0 + k];
        }
        // Load B tile: 16 k x 64 n (n fastest -> fully coalesced)
        #pragma unroll
        for (int i = 0; i < 4; ++i) {
            int idx = tid + i * 256;
            int k = idx >> 6;
            int n = idx & 63;
            Bs[k][n] = B[(size_t)(k0 + k) * N + colBase + n];
        }
        __syncthreads();
        #pragma unroll
        for (int k = 0; k < BK; ++k) {
            float a[4], b[4];
            #pragma unroll
            for (int i = 0; i < 4; ++i) a[i] = As[k][ty + i * 16];
            #pragma unroll
            for (int j = 0; j < 4; ++j) b[j] = Bs[k][tx + j * 16];
            #pragma unroll
            for (int i = 0; i < 4; ++i)
                #pragma unroll
                for (int j = 0; j < 4; ++j)
                    acc[i][j] += a[i] * b[j];
        }
        __syncthreads();
    }

    #pragma unroll
    for (int i = 0; i < 4; ++i) {
        int row = rowBase + ty + i * 16;
        #pragma unroll
        for (int j = 0; j < 4; ++j)
            C[(size_t)row * N + colBase + tx + j * 16] = acc[i][j];
    }
}

// ---------------------------------------------------------------------------
// Scan phase A: per-chunk carry with zero initial state.
// carry[b,c,n] = sum_{j=0..LC-1} A[n]^(LC-1-j) * uB[b, c*LC+j, n]
// grid (BATCH, NC), block 256 (= STATE) threads; lane n fastest -> coalesced.
// ---------------------------------------------------------------------------
__global__ __launch_bounds__(256) void scan_carry(
    const float* __restrict__ uB, const float* __restrict__ A,
    float* __restrict__ carry)
{
    const int b = blockIdx.x;
    const int c = blockIdx.y;
    const int n = threadIdx.x;
    const float a = A[n];
    const float* p = uB + ((size_t)b * LENGTH + (size_t)c * LC) * STATE + n;
    float s = 0.f;
    #pragma unroll 8
    for (int j = 0; j < LC; ++j) s = a * s + p[(size_t)j * STATE];
    carry[((size_t)b * NC + c) * STATE + n] = s;
}

// ---------------------------------------------------------------------------
// Scan phase B: sequential combine over chunks (tiny).
// h[b,c,n] = state entering chunk c.  h[b,0]=x0;  h[b,c]=A^LC * h[b,c-1] + carry[b,c-1]
// grid BATCH, block 256.
// ---------------------------------------------------------------------------
__global__ __launch_bounds__(256) void scan_combine(
    const float* __restrict__ carry, const float* __restrict__ A,
    const float* __restrict__ x0, float* __restrict__ h)
{
    const int b = blockIdx.x;
    const int n = threadIdx.x;
    const float a = A[n];
    float a2 = a * a, a4 = a2 * a2, a8 = a4 * a4, a16 = a8 * a8, a32 = a16 * a16;
    const float aLC = a32 * a32;   // a^64 == a^LC
    float s = x0[(size_t)b * STATE + n];
    for (int c = 0; c < NC; ++c) {
        h[((size_t)b * NC + c) * STATE + n] = s;
        s = aLC * s + carry[((size_t)b * NC + c) * STATE + n];
    }
}

// ---------------------------------------------------------------------------
// Scan phase C: re-apply recurrence with correct initial state; write x.
// Also writes x[:, L-1] (second output) from the last chunk.
// ---------------------------------------------------------------------------
__global__ __launch_bounds__(256) void scan_apply(
    const float* __restrict__ uB, const float* __restrict__ A,
    const float* __restrict__ h, float* __restrict__ x,
    float* __restrict__ x_last)
{
    const int b = blockIdx.x;
    const int c = blockIdx.y;
    const int n = threadIdx.x;
    const float a = A[n];
    float s = h[((size_t)b * NC + c) * STATE + n];
    const float* p = uB + ((size_t)b * LENGTH + (size_t)c * LC) * STATE + n;
    float* q = x + ((size_t)b * LENGTH + (size_t)c * LC) * STATE + n;
    #pragma unroll 8
    for (int j = 0; j < LC; ++j) {
        s = a * s + p[(size_t)j * STATE];
        q[(size_t)j * STATE] = s;
    }
    if (c == NC - 1) x_last[(size_t)b * STATE + n] = s;
}

// ---------------------------------------------------------------------------
extern "C" void kernel_launch(void* const* d_in, const int* in_sizes, int n_in,
                              void* d_out, int out_size, void* d_ws, size_t ws_size,
                              hipStream_t stream)
{
    const float* u  = (const float*)d_in[0];   // [8,4096,512]
    const float* x0 = (const float*)d_in[1];   // [8,256]
    const float* A  = (const float*)d_in[2];   // [256]
    const float* B  = (const float*)d_in[3];   // [512,256]
    const float* C  = (const float*)d_in[4];   // [256,512]

    float* y      = (float*)d_out;                                   // [8,4096,512]
    float* x_last = y + (size_t)BATCH * LENGTH * OUT_DIM;            // [8,256]

    char* ws = (char*)d_ws;
    float* uB    = (float*)(ws);                                     // 32 MB
    float* x     = (float*)(ws + (size_t)32 * 1024 * 1024);          // 32 MB
    float* carry = (float*)(ws + (size_t)64 * 1024 * 1024);          // 512 KB
    float* h     = (float*)(ws + (size_t)64 * 1024 * 1024 + 524288); // 512 KB

    const int M = BATCH * LENGTH;   // 32768
    dim3 blk(256);

    // GEMM1: uB[M,STATE] = u[M,IN] @ B[IN,STATE]
    dim3 g1(STATE / TILE, M / TILE);
    gemm_f32_tile64<<<g1, blk, 0, stream>>>(u, B, uB, M, STATE, IN_DIM);

    // chunked scan
    scan_carry  <<<dim3(BATCH, NC), blk, 0, stream>>>(uB, A, carry);
    scan_combine<<<dim3(BATCH),     blk, 0, stream>>>(carry, A, x0, h);
    scan_apply  <<<dim3(BATCH, NC), blk, 0, stream>>>(uB, A, h, x, x_last);

    // GEMM2: y[M,OUT] = x[M,STATE] @ C[STATE,OUT]
    dim3 g2(OUT_DIM / TILE, M / TILE);
    gemm_f32_tile64<<<g2, blk, 0, stream>>>(x, C, y, M, OUT_DIM, STATE);
}

// Round 2
// 222.825 us; speedup vs baseline: 1.9213x; 1.9213x over previous
//
#include <hip/hip_runtime.h>

#define BATCH   8
#define LENGTH  4096
#define IN_DIM  512
#define STATE   256
#define OUT_DIM 512
#define NC      64          // chunks along L
#define LC      64          // LENGTH / NC

typedef __attribute__((ext_vector_type(8))) short bf16x8;
typedef __attribute__((ext_vector_type(4))) float f32x4;

__device__ __forceinline__ unsigned short bf16_rne(float v) {
    unsigned u = __builtin_bit_cast(unsigned, v);
    unsigned r = (u + 0x7FFFu + ((u >> 16) & 1u)) >> 16;
    return (unsigned short)r;
}
__device__ __forceinline__ float bf16_f(unsigned short h) {
    unsigned u = ((unsigned)h) << 16;
    return __builtin_bit_cast(float, u);
}

// ---------------------------------------------------------------------------
// Split fp32 array -> hi/lo bf16 planes (same layout). n multiple of 1024.
// ---------------------------------------------------------------------------
__global__ __launch_bounds__(256) void split_u_kernel(
    const float* __restrict__ in, unsigned short* __restrict__ hi,
    unsigned short* __restrict__ lo)
{
    size_t i = ((size_t)blockIdx.x * 256 + threadIdx.x) * 4;
    float4 v = *(const float4*)(in + i);
    ushort4 h, l;
    h.x = bf16_rne(v.x); l.x = bf16_rne(v.x - bf16_f(h.x));
    h.y = bf16_rne(v.y); l.y = bf16_rne(v.y - bf16_f(h.y));
    h.z = bf16_rne(v.z); l.z = bf16_rne(v.z - bf16_f(h.z));
    h.w = bf16_rne(v.w); l.w = bf16_rne(v.w - bf16_f(h.w));
    *(ushort4*)(hi + i) = h;
    *(ushort4*)(lo + i) = l;
}

// ---------------------------------------------------------------------------
// Split + transpose a weight: in[K][Nsrc] fp32 -> hi/lo bf16 [Nsrc][K].
// id enumerates output [n][k], k fastest (coalesced writes). K = 1<<kbits.
// ---------------------------------------------------------------------------
__global__ __launch_bounds__(256) void split_T_kernel(
    const float* __restrict__ in, unsigned short* __restrict__ hi,
    unsigned short* __restrict__ lo, int kbits, int Nsrc)
{
    int id = blockIdx.x * 256 + threadIdx.x;
    int k = id & ((1 << kbits) - 1);
    int n = id >> kbits;
    float v = in[(size_t)k * Nsrc + n];
    unsigned short h = bf16_rne(v);
    hi[id] = h;
    lo[id] = bf16_rne(v - bf16_f(h));
}

// ---------------------------------------------------------------------------
// Split-bf16 MFMA GEMM: C[M][N] = A[M][K] * B^T where operands are given as
// hi/lo bf16 planes, A row-major [M][K], B transposed row-major [N][K].
// Exact-ish: acc += Ahi*Bhi + Alo*Bhi + Ahi*Blo  (fp32 accumulate).
// Block: 256 thr = 4 waves, tile 128x128, BK=32, 16x16x32 bf16 MFMA.
// grid = (N/128, M/128)  (N-cols on x for A-tile L2 reuse).
//
// LDS: 4 planes (Ahi,Alo,Bhi,Blo), each 128 rows x 32 k bf16 = 8KB,
// stored in 16B "slots": physical slot = row*4 + (kgrp ^ ((row>>1)&3)).
// The XOR swizzle makes ds_read_b128 frag reads hit each bank-quad <=2x
// while staging stays a contiguous wave-uniform global_load_lds target
// (we invert the swizzle on the *global* address side).
// ---------------------------------------------------------------------------
__global__ __launch_bounds__(256) void gemm_split(
    const unsigned short* __restrict__ Ahi, const unsigned short* __restrict__ Alo,
    const unsigned short* __restrict__ Bhi, const unsigned short* __restrict__ Blo,
    float* __restrict__ Cc, int N_, int K)
{
    __shared__ unsigned short lds[4 * 512 * 8];   // 32 KB

    const int tid  = threadIdx.x;
    const int wave = tid >> 6;
    const int lane = tid & 63;
    const int n0 = blockIdx.x * 128;
    const int m0 = blockIdx.y * 128;

    // wave w stages plane w: 0=Ahi 1=Alo 2=Bhi 3=Blo; 8 insts x 64 lanes x 16B
    const unsigned short* op =
        (wave == 0) ? Ahi : (wave == 1) ? Alo : (wave == 2) ? Bhi : Blo;
    const int rowBase = (wave < 2) ? m0 : n0;

    const unsigned short* g[8];
    #pragma unroll
    for (int i = 0; i < 8; ++i) {
        int p = i * 64 + lane;                 // physical slot within plane
        int row = p >> 2;
        int kg = (p & 3) ^ ((row >> 1) & 3);   // inverse swizzle
        g[i] = op + (size_t)(rowBase + row) * K + kg * 8;
    }

    const int r = lane & 15, q = lane >> 4;
    const int wm = (wave >> 1) * 64, wn = (wave & 1) * 64;

    // frag read offsets (ushort index): slot(row, kgrp=q) * 8
    int aoff[4], boff[4];
    #pragma unroll
    for (int i = 0; i < 4; ++i) {
        int row = wm + i * 16 + r;
        aoff[i] = (row * 4 + (q ^ ((row >> 1) & 3))) * 8;
        row = wn + i * 16 + r;
        boff[i] = (row * 4 + (q ^ ((row >> 1) & 3))) * 8;
    }

    f32x4 acc[4][4];
    #pragma unroll
    for (int i = 0; i < 4; ++i)
        #pragma unroll
        for (int j = 0; j < 4; ++j)
            acc[i][j] = (f32x4){0.f, 0.f, 0.f, 0.f};

    for (int k0 = 0; k0 < K; k0 += 32) {
        #pragma unroll
        for (int i = 0; i < 8; ++i) {
            __builtin_amdgcn_global_load_lds(
                (const __attribute__((address_space(1))) unsigned int*)(g[i]),
                (__attribute__((address_space(3))) unsigned int*)(&lds[wave * 4096 + i * 512]),
                16, 0, 0);
            g[i] += 32;    // advance one BK step (32 bf16 = 64B)
        }
        __syncthreads();   // drains vmcnt then barrier

        bf16x8 ahi[4], alo[4], bhi[4], blo[4];
        #pragma unroll
        for (int i = 0; i < 4; ++i) {
            ahi[i] = *(const bf16x8*)(&lds[        aoff[i]]);
            alo[i] = *(const bf16x8*)(&lds[ 4096 + aoff[i]]);
            bhi[i] = *(const bf16x8*)(&lds[ 8192 + boff[i]]);
            blo[i] = *(const bf16x8*)(&lds[12288 + boff[i]]);
        }
        #pragma unroll
        for (int i = 0; i < 4; ++i)
            #pragma unroll
            for (int j = 0; j < 4; ++j) {
                acc[i][j] = __builtin_amdgcn_mfma_f32_16x16x32_bf16(ahi[i], bhi[j], acc[i][j], 0, 0, 0);
                acc[i][j] = __builtin_amdgcn_mfma_f32_16x16x32_bf16(alo[i], bhi[j], acc[i][j], 0, 0, 0);
                acc[i][j] = __builtin_amdgcn_mfma_f32_16x16x32_bf16(ahi[i], blo[j], acc[i][j], 0, 0, 0);
            }
        __syncthreads();
    }

    // C/D layout: col = lane&15, row = q*4 + reg  [m89-verified]
    #pragma unroll
    for (int i = 0; i < 4; ++i) {
        #pragma unroll
        for (int reg = 0; reg < 4; ++reg) {
            int mg = m0 + wm + i * 16 + q * 4 + reg;
            float* dst = Cc + (size_t)mg * N_ + n0 + wn + r;
            #pragma unroll
            for (int j = 0; j < 4; ++j)
                dst[j * 16] = acc[i][j][reg];
        }
    }
}

// ---------------------------------------------------------------------------
// Scan phase A: per-chunk carry with zero initial state.
// ---------------------------------------------------------------------------
__global__ __launch_bounds__(256) void scan_carry(
    const float* __restrict__ uB, const float* __restrict__ A,
    float* __restrict__ carry)
{
    const int b = blockIdx.x;
    const int c = blockIdx.y;
    const int n = threadIdx.x;
    const float a = A[n];
    const float* p = uB + ((size_t)b * LENGTH + (size_t)c * LC) * STATE + n;
    float s = 0.f;
    #pragma unroll 8
    for (int j = 0; j < LC; ++j) s = a * s + p[(size_t)j * STATE];
    carry[((size_t)b * NC + c) * STATE + n] = s;
}

// ---------------------------------------------------------------------------
// Scan phase B: sequential combine over chunks (tiny).
// ---------------------------------------------------------------------------
__global__ __launch_bounds__(256) void scan_combine(
    const float* __restrict__ carry, const float* __restrict__ A,
    const float* __restrict__ x0, float* __restrict__ h)
{
    const int b = blockIdx.x;
    const int n = threadIdx.x;
    const float a = A[n];
    float a2 = a * a, a4 = a2 * a2, a8 = a4 * a4, a16 = a8 * a8, a32 = a16 * a16;
    const float aLC = a32 * a32;   // a^64
    float s = x0[(size_t)b * STATE + n];
    for (int c = 0; c < NC; ++c) {
        h[((size_t)b * NC + c) * STATE + n] = s;
        s = aLC * s + carry[((size_t)b * NC + c) * STATE + n];
    }
}

// ---------------------------------------------------------------------------
// Scan phase C: re-apply with correct initial state; write x as hi/lo bf16
// planes (GEMM2 A-operand) + x_last fp32 (second output).
// ---------------------------------------------------------------------------
__global__ __launch_bounds__(256) void scan_apply(
    const float* __restrict__ uB, const float* __restrict__ A,
    const float* __restrict__ h, unsigned short* __restrict__ x_hi,
    unsigned short* __restrict__ x_lo, float* __restrict__ x_last)
{
    const int b = blockIdx.x;
    const int c = blockIdx.y;
    const int n = threadIdx.x;
    const float a = A[n];
    float s = h[((size_t)b * NC + c) * STATE + n];
    const size_t base = ((size_t)b * LENGTH + (size_t)c * LC) * STATE + n;
    const float* p = uB + base;
    #pragma unroll 4
    for (int j = 0; j < LC; ++j) {
        s = a * s + p[(size_t)j * STATE];
        unsigned short hh = bf16_rne(s);
        x_hi[base + (size_t)j * STATE] = hh;
        x_lo[base + (size_t)j * STATE] = bf16_rne(s - bf16_f(hh));
    }
    if (c == NC - 1) x_last[(size_t)b * STATE + n] = s;
}

// ---------------------------------------------------------------------------
extern "C" void kernel_launch(void* const* d_in, const int* in_sizes, int n_in,
                              void* d_out, int out_size, void* d_ws, size_t ws_size,
                              hipStream_t stream)
{
    const float* u  = (const float*)d_in[0];   // [8,4096,512]
    const float* x0 = (const float*)d_in[1];   // [8,256]
    const float* A  = (const float*)d_in[2];   // [256]
    const float* B  = (const float*)d_in[3];   // [512,256]
    const float* C  = (const float*)d_in[4];   // [256,512]

    const size_t MB = 1024 * 1024;
    char* ws = (char*)d_ws;

    unsigned short* u_hi = (unsigned short*)(ws);             // 32 MB
    unsigned short* u_lo = (unsigned short*)(ws + 32 * MB);   // 32 MB
    unsigned short* x_hi = (unsigned short*)(ws);             // 16 MB (reuse u_hi, dead after GEMM1)
    unsigned short* x_lo = (unsigned short*)(ws + 16 * MB);   // 16 MB
    float* carry = (float*)(ws + 64 * MB);                    // 512 KB
    float* h     = (float*)(ws + 64 * MB + 512 * 1024);       // 512 KB
    unsigned short* Bt_hi = (unsigned short*)(ws + 65 * MB);                // 256 KB
    unsigned short* Bt_lo = (unsigned short*)(ws + 65 * MB + 256 * 1024);   // 256 KB
    unsigned short* Ct_hi = (unsigned short*)(ws + 65 * MB + 512 * 1024);   // 256 KB
    unsigned short* Ct_lo = (unsigned short*)(ws + 65 * MB + 768 * 1024);   // 256 KB

    float* y      = (float*)d_out;                              // [8,4096,512] = 64 MB
    float* x_last = y + (size_t)BATCH * LENGTH * OUT_DIM;       // [8,256]
    // uB parks in the upper half of y's region; dead before GEMM2 writes y.
    float* uB     = (float*)((char*)d_out + 32 * MB);           // [8,4096,256] = 32 MB

    const int M = BATCH * LENGTH;   // 32768
    dim3 blk(256);

    // 1. split inputs to bf16 hi/lo planes
    split_u_kernel<<<dim3((M * IN_DIM) / 1024), blk, 0, stream>>>(u, u_hi, u_lo);
    split_T_kernel<<<dim3((IN_DIM * STATE) / 256), blk, 0, stream>>>(B, Bt_hi, Bt_lo, 9, STATE);   // Bt[256][512]
    split_T_kernel<<<dim3((STATE * OUT_DIM) / 256), blk, 0, stream>>>(C, Ct_hi, Ct_lo, 8, OUT_DIM); // Ct[512][256]

    // 2. GEMM1: uB[M,STATE] = u @ B   (A=[M,512], Bt=[256,512])
    gemm_split<<<dim3(STATE / 128, M / 128), blk, 0, stream>>>(
        u_hi, u_lo, Bt_hi, Bt_lo, uB, STATE, IN_DIM);

    // 3. chunked scan (fp32 exact)
    scan_carry  <<<dim3(BATCH, NC), blk, 0, stream>>>(uB, A, carry);
    scan_combine<<<dim3(BATCH),     blk, 0, stream>>>(carry, A, x0, h);
    scan_apply  <<<dim3(BATCH, NC), blk, 0, stream>>>(uB, A, h, x_hi, x_lo, x_last);

    // 4. GEMM2: y[M,OUT] = x @ C   (A=[M,256], Ct=[512,256])
    gemm_split<<<dim3(OUT_DIM / 128, M / 128), blk, 0, stream>>>(
        x_hi, x_lo, Ct_hi, Ct_lo, y, OUT_DIM, STATE);
}

// Round 3
// 209.169 us; speedup vs baseline: 2.0467x; 1.0653x over previous
//
#include <hip/hip_runtime.h>

#define BATCH   8
#define LENGTH  4096
#define IN_DIM  512
#define STATE   256
#define OUT_DIM 512
#define NC      64
#define LC      64

typedef __attribute__((ext_vector_type(8))) short bf16x8;
typedef __attribute__((ext_vector_type(4))) float f32x4;

union FragU { bf16x8 v; unsigned u[4]; };

__device__ __forceinline__ unsigned short bf16_rne(float v) {
    unsigned u = __builtin_bit_cast(unsigned, v);
    unsigned r = (u + 0x7FFFu + ((u >> 16) & 1u)) >> 16;
    return (unsigned short)r;
}
__device__ __forceinline__ float bf16_f(unsigned short h) {
    unsigned u = ((unsigned)h) << 16;
    return __builtin_bit_cast(float, u);
}

// ---------------------------------------------------------------------------
// Split + transpose a weight: in[K][Nsrc] fp32 -> hi/lo bf16 [Nsrc][K] (RNE).
// ---------------------------------------------------------------------------
__global__ __launch_bounds__(256) void split_T_kernel(
    const float* __restrict__ in, unsigned short* __restrict__ hi,
    unsigned short* __restrict__ lo, int kbits, int Nsrc)
{
    int id = blockIdx.x * 256 + threadIdx.x;
    int k = id & ((1 << kbits) - 1);
    int n = id >> kbits;
    float v = in[(size_t)k * Nsrc + n];
    unsigned short h = bf16_rne(v);
    hi[id] = h;
    lo[id] = bf16_rne(v - bf16_f(h));
}

// ---------------------------------------------------------------------------
// Split-bf16 MFMA GEMM, A read as fp32 (in-register hi/lo split):
//   C[M][N] = A[M][K] (fp32) * Bt[N][K] (pre-split hi/lo bf16 planes)
//   acc += Ahi*Bhi + Alo*Bhi + Ahi*Blo   (fp32 accumulate)
// Block: 512 thr = 8 waves (each 64x32), tile 128x128, BK=32.
// LDS double-buffered (2 x 32KB): per buffer A fp32 16KB + Bhi 8KB + Blo 8KB.
// K-loop uses raw s_barrier + manual s_waitcnt vmcnt(4): the prefetch for
// iter t+1 stays in flight across the barrier (no vmcnt(0) drain).
//
// A LDS layout: row = 128B = 8 slots of 16B; phys slot = l ^ (row&7)
//   (l = logical k-chunk). Quarter-wave frag reads hit each bank twice (free).
// B LDS layout: row = 64B = 4 slots; phys = l ^ ((row>>1)&3)  (round-2, 0 confl).
// Staging inverts the swizzle on the GLOBAL address side so the LDS dst is
// wave-uniform-base + lane*16 (global_load_lds requirement).
// ---------------------------------------------------------------------------
__global__ __launch_bounds__(512, 4) void gemm_dbuf(
    const float* __restrict__ Af, const unsigned short* __restrict__ Bthi,
    const unsigned short* __restrict__ Btlo, float* __restrict__ Cc,
    int N_, int K)
{
    __shared__ unsigned short lds[2 * 16384];   // 64 KB

    const int tid  = threadIdx.x;
    const int wave = tid >> 6;
    const int lane = tid & 63;
    const int n0 = blockIdx.x * 128;
    const int m0 = blockIdx.y * 128;

    // --- staging descriptors: 32 wave-instructions of 1KB; 4 per wave ---
    const char* gp[4];
    int ldsoff[4], gstep[4];
    #pragma unroll
    for (int t = 0; t < 4; ++t) {
        int gi = wave * 4 + t;
        if (gi < 16) {          // A plane: 1024 slots (16 KB)
            int p = gi * 64 + lane;
            int row = p >> 3, s = p & 7;
            int l = s ^ (row & 7);
            gp[t] = (const char*)(Af + (size_t)(m0 + row) * K + l * 4);
            gstep[t] = 32 * 4;              // BK fp32
            ldsoff[t] = gi * 512;
        } else {                // B planes: 512 slots each (8 KB)
            int q2 = (gi - 16) >> 3;        // 0 = hi, 1 = lo
            int pi = gi & 7;
            int p = pi * 64 + lane;
            int row = p >> 2, s = p & 3;
            int l = s ^ ((row >> 1) & 3);
            const unsigned short* base = q2 ? Btlo : Bthi;
            gp[t] = (const char*)(base + (size_t)(n0 + row) * K + l * 8);
            gstep[t] = 32 * 2;              // BK bf16
            ldsoff[t] = 8192 + q2 * 4096 + pi * 512;
        }
    }

    const int r = lane & 15, q = lane >> 4;
    const int wm = (wave >> 2) * 64, wn = (wave & 3) * 32;

    // fragment read offsets (ushort units, within one buffer)
    int aoff[4][2], boff[2];
    #pragma unroll
    for (int i = 0; i < 4; ++i) {
        int row = wm + i * 16 + r;
        #pragma unroll
        for (int h = 0; h < 2; ++h)
            aoff[i][h] = row * 64 + ((2 * q + h) ^ (row & 7)) * 8;
    }
    #pragma unroll
    for (int j = 0; j < 2; ++j) {
        int row = wn + j * 16 + r;
        boff[j] = row * 32 + (q ^ ((row >> 1) & 3)) * 8;
    }

    f32x4 acc[4][2];
    #pragma unroll
    for (int i = 0; i < 4; ++i)
        #pragma unroll
        for (int j = 0; j < 2; ++j)
            acc[i][j] = (f32x4){0.f, 0.f, 0.f, 0.f};

    // prologue: stage buffer 0
    #pragma unroll
    for (int t = 0; t < 4; ++t) {
        __builtin_amdgcn_global_load_lds(
            (const __attribute__((address_space(1))) unsigned*)(gp[t]),
            (__attribute__((address_space(3))) unsigned*)(&lds[ldsoff[t]]),
            16, 0, 0);
        gp[t] += gstep[t];
    }

    const int nit = K >> 5;
    for (int it = 0; it < nit; ++it) {
        // barrier 1: everyone done computing on the buffer we're about to fill
        asm volatile("" ::: "memory");
        __builtin_amdgcn_s_barrier();
        asm volatile("" ::: "memory");
        if (it + 1 < nit) {
            const int bb = ((it + 1) & 1) * 16384;
            #pragma unroll
            for (int t = 0; t < 4; ++t) {
                __builtin_amdgcn_global_load_lds(
                    (const __attribute__((address_space(1))) unsigned*)(gp[t]),
                    (__attribute__((address_space(3))) unsigned*)(&lds[bb + ldsoff[t]]),
                    16, 0, 0);
                gp[t] += gstep[t];
            }
            __builtin_amdgcn_s_waitcnt(0x0F74);   // vmcnt(4): current buf done, prefetch flying
        } else {
            __builtin_amdgcn_s_waitcnt(0x0F70);   // vmcnt(0)
        }
        asm volatile("" ::: "memory");
        __builtin_amdgcn_s_barrier();             // barrier 2: current buf visible to all
        asm volatile("" ::: "memory");

        const unsigned short* buf = &lds[(it & 1) * 16384];

        // A fragments: fp32 -> hi/lo bf16 (trunc split, v_perm packing)
        FragU ahi[4], alo[4];
        #pragma unroll
        for (int i = 0; i < 4; ++i) {
            #pragma unroll
            for (int h = 0; h < 2; ++h) {
                float4 f = *(const float4*)(buf + aoff[i][h]);
                unsigned bx = __builtin_bit_cast(unsigned, f.x);
                unsigned by = __builtin_bit_cast(unsigned, f.y);
                unsigned bz = __builtin_bit_cast(unsigned, f.z);
                unsigned bw = __builtin_bit_cast(unsigned, f.w);
                ahi[i].u[h * 2]     = __builtin_amdgcn_perm(by, bx, 0x07060302);
                ahi[i].u[h * 2 + 1] = __builtin_amdgcn_perm(bw, bz, 0x07060302);
                float lx = f.x - __builtin_bit_cast(float, bx & 0xFFFF0000u);
                float ly = f.y - __builtin_bit_cast(float, by & 0xFFFF0000u);
                float lz = f.z - __builtin_bit_cast(float, bz & 0xFFFF0000u);
                float lw = f.w - __builtin_bit_cast(float, bw & 0xFFFF0000u);
                alo[i].u[h * 2]     = __builtin_amdgcn_perm(
                    __builtin_bit_cast(unsigned, ly), __builtin_bit_cast(unsigned, lx), 0x07060302);
                alo[i].u[h * 2 + 1] = __builtin_amdgcn_perm(
                    __builtin_bit_cast(unsigned, lw), __builtin_bit_cast(unsigned, lz), 0x07060302);
            }
        }
        FragU bhi[2], blo[2];
        #pragma unroll
        for (int j = 0; j < 2; ++j) {
            bhi[j].v = *(const bf16x8*)(buf +  8192 + boff[j]);
            blo[j].v = *(const bf16x8*)(buf + 12288 + boff[j]);
        }
        #pragma unroll
        for (int i = 0; i < 4; ++i)
            #pragma unroll
            for (int j = 0; j < 2; ++j) {
                acc[i][j] = __builtin_amdgcn_mfma_f32_16x16x32_bf16(ahi[i].v, bhi[j].v, acc[i][j], 0, 0, 0);
                acc[i][j] = __builtin_amdgcn_mfma_f32_16x16x32_bf16(alo[i].v, bhi[j].v, acc[i][j], 0, 0, 0);
                acc[i][j] = __builtin_amdgcn_mfma_f32_16x16x32_bf16(ahi[i].v, blo[j].v, acc[i][j], 0, 0, 0);
            }
    }

    // epilogue: C/D layout col = lane&15, row = q*4 + reg
    #pragma unroll
    for (int i = 0; i < 4; ++i) {
        #pragma unroll
        for (int reg = 0; reg < 4; ++reg) {
            int mg = m0 + wm + i * 16 + q * 4 + reg;
            float* dst = Cc + (size_t)mg * N_ + n0 + wn + r;
            dst[0]  = acc[i][0][reg];
            dst[16] = acc[i][1][reg];
        }
    }
}

// ---------------------------------------------------------------------------
// Scan phase A: per-chunk carry with zero initial state.
// ---------------------------------------------------------------------------
__global__ __launch_bounds__(256) void scan_carry(
    const float* __restrict__ uB, const float* __restrict__ A,
    float* __restrict__ carry)
{
    const int b = blockIdx.x;
    const int c = blockIdx.y;
    const int n = threadIdx.x;
    const float a = A[n];
    const float* p = uB + ((size_t)b * LENGTH + (size_t)c * LC) * STATE + n;
    float s = 0.f;
    #pragma unroll 8
    for (int j = 0; j < LC; ++j) s = a * s + p[(size_t)j * STATE];
    carry[((size_t)b * NC + c) * STATE + n] = s;
}

// ---------------------------------------------------------------------------
// Scan phase B (fused combine+apply): block (b,c) rebuilds its entry state
// from the carries (<=63 independent loads + FMA chain), then re-applies the
// recurrence writing x fp32; last chunk also writes x_last.
// ---------------------------------------------------------------------------
__global__ __launch_bounds__(256) void scan_apply(
    const float* __restrict__ uB, const float* __restrict__ A,
    const float* __restrict__ carry, const float* __restrict__ x0,
    float* __restrict__ x, float* __restrict__ x_last)
{
    const int b = blockIdx.x;
    const int c = blockIdx.y;
    const int n = threadIdx.x;
    const float a = A[n];
    float a2 = a * a, a4 = a2 * a2, a8 = a4 * a4, a16 = a8 * a8, a32 = a16 * a16;
    const float aLC = a32 * a32;   // a^64

    float s = x0[(size_t)b * STATE + n];
    for (int d = 0; d < c; ++d)
        s = aLC * s + carry[((size_t)b * NC + d) * STATE + n];

    const size_t base = ((size_t)b * LENGTH + (size_t)c * LC) * STATE + n;
    const float* p = uB + base;
    float* qx = x + base;
    #pragma unroll 8
    for (int j = 0; j < LC; ++j) {
        s = a * s + p[(size_t)j * STATE];
        qx[(size_t)j * STATE] = s;
    }
    if (c == NC - 1) x_last[(size_t)b * STATE + n] = s;
}

// ---------------------------------------------------------------------------
extern "C" void kernel_launch(void* const* d_in, const int* in_sizes, int n_in,
                              void* d_out, int out_size, void* d_ws, size_t ws_size,
                              hipStream_t stream)
{
    const float* u  = (const float*)d_in[0];   // [8,4096,512]
    const float* x0 = (const float*)d_in[1];   // [8,256]
    const float* A  = (const float*)d_in[2];   // [256]
    const float* B  = (const float*)d_in[3];   // [512,256]
    const float* C  = (const float*)d_in[4];   // [256,512]

    const size_t MB = 1024 * 1024;
    char* ws = (char*)d_ws;

    float* x     = (float*)(ws);                               // [M,256] fp32, 32 MB
    float* carry = (float*)(ws + 32 * MB);                     // 512 KB
    unsigned short* Bt_hi = (unsigned short*)(ws + 33 * MB);                // 256 KB
    unsigned short* Bt_lo = (unsigned short*)(ws + 33 * MB + 256 * 1024);   // 256 KB
    unsigned short* Ct_hi = (unsigned short*)(ws + 33 * MB + 512 * 1024);   // 256 KB
    unsigned short* Ct_lo = (unsigned short*)(ws + 33 * MB + 768 * 1024);   // 256 KB

    float* y      = (float*)d_out;                             // [8,4096,512] = 64 MB
    float* x_last = y + (size_t)BATCH * LENGTH * OUT_DIM;      // [8,256]
    // uB parks in the upper half of y's region; dead before GEMM2 writes y.
    float* uB     = (float*)((char*)d_out + 32 * MB);          // [M,256] = 32 MB

    const int M = BATCH * LENGTH;   // 32768

    // 1. split+transpose weights to bf16 hi/lo planes
    split_T_kernel<<<dim3((IN_DIM * STATE) / 256), dim3(256), 0, stream>>>(B, Bt_hi, Bt_lo, 9, STATE);
    split_T_kernel<<<dim3((STATE * OUT_DIM) / 256), dim3(256), 0, stream>>>(C, Ct_hi, Ct_lo, 8, OUT_DIM);

    // 2. GEMM1: uB[M,256] = u[M,512] @ B  (A fp32 direct, split in-register)
    gemm_dbuf<<<dim3(STATE / 128, M / 128), dim3(512), 0, stream>>>(
        u, Bt_hi, Bt_lo, uB, STATE, IN_DIM);

    // 3. chunked scan (fp32 exact), combine fused into apply
    scan_carry<<<dim3(BATCH, NC), dim3(256), 0, stream>>>(uB, A, carry);
    scan_apply<<<dim3(BATCH, NC), dim3(256), 0, stream>>>(uB, A, carry, x0, x, x_last);

    // 4. GEMM2: y[M,512] = x[M,256] @ C
    gemm_dbuf<<<dim3(OUT_DIM / 128, M / 128), dim3(512), 0, stream>>>(
        x, Ct_hi, Ct_lo, y, OUT_DIM, STATE);
}